// Round 1
// baseline (58.820 us; speedup 1.0000x reference)
//
#include <hip/hip_runtime.h>

// QuantileLoss: mean over (N,5) loss matrix.
//   cols 0-2: (preds[:,0:3] - target[:,0:3])^2
//   col 3: lower = p_lo>p_mid ? 1000 : (p_lo > 0.95*t ? 0 : (p_lo-t)^2)
//   col 4: upper = p_hi<p_mid ? 1000 : (p_hi < 1.05*t ? 0 : (p_hi-t)^2)
// preds (N,6) f32, target (N,4) f32, out: 1 f32 scalar.

#define QL_BLOCKS 2048
#define QL_THREADS 256

__global__ __launch_bounds__(QL_THREADS)
void ql_partial(const float* __restrict__ preds,
                const float* __restrict__ target,
                float* __restrict__ partial,
                int npairs) {
    const float PEN = 1000.0f;
    int tid = blockIdx.x * blockDim.x + threadIdx.x;
    int stride = gridDim.x * blockDim.x;
    float sum = 0.0f;

    for (int i = tid; i < npairs; i += stride) {
        // 2 preds rows = 3 x float4 (48B aligned), 2 target rows = 2 x float4
        const float4* pp = reinterpret_cast<const float4*>(preds + (size_t)i * 12);
        const float4* tt = reinterpret_cast<const float4*>(target + (size_t)i * 8);
        float4 a = pp[0];
        float4 b = pp[1];
        float4 c = pp[2];
        float4 ta = tt[0];
        float4 tb = tt[1];

        // row 0: preds = a.x a.y a.z a.w b.x b.y ; target = ta
        {
            float d0 = a.x - ta.x, d1 = a.y - ta.y, d2 = a.z - ta.z;
            sum += d0 * d0 + d1 * d1 + d2 * d2;
            float pm = a.w, pl = b.x, ph = b.y, t = ta.w;
            float dl = pl - t, du = ph - t;
            float lower = (pl > pm) ? PEN : ((pl > t * 0.95f) ? 0.0f : dl * dl);
            float upper = (ph < pm) ? PEN : ((ph < t * 1.05f) ? 0.0f : du * du);
            sum += lower + upper;
        }
        // row 1: preds = b.z b.w c.x c.y c.z c.w ; target = tb
        {
            float d0 = b.z - tb.x, d1 = b.w - tb.y, d2 = c.x - tb.z;
            sum += d0 * d0 + d1 * d1 + d2 * d2;
            float pm = c.y, pl = c.z, ph = c.w, t = tb.w;
            float dl = pl - t, du = ph - t;
            float lower = (pl > pm) ? PEN : ((pl > t * 0.95f) ? 0.0f : dl * dl);
            float upper = (ph < pm) ? PEN : ((ph < t * 1.05f) ? 0.0f : du * du);
            sum += lower + upper;
        }
    }

    // wave64 shuffle reduction
    #pragma unroll
    for (int off = 32; off > 0; off >>= 1)
        sum += __shfl_down(sum, off, 64);

    __shared__ float wsum[QL_THREADS / 64];
    int lane = threadIdx.x & 63;
    int wid = threadIdx.x >> 6;
    if (lane == 0) wsum[wid] = sum;
    __syncthreads();
    if (threadIdx.x == 0) {
        float s = 0.0f;
        #pragma unroll
        for (int w = 0; w < QL_THREADS / 64; ++w) s += wsum[w];
        partial[blockIdx.x] = s;
    }
}

__global__ __launch_bounds__(QL_THREADS)
void ql_final(const float* __restrict__ partial,
              float* __restrict__ out,
              int n, double inv_count) {
    double s = 0.0;
    for (int i = threadIdx.x; i < n; i += blockDim.x)
        s += (double)partial[i];

    #pragma unroll
    for (int off = 32; off > 0; off >>= 1)
        s += __shfl_down(s, off, 64);

    __shared__ double wsum[QL_THREADS / 64];
    int lane = threadIdx.x & 63;
    int wid = threadIdx.x >> 6;
    if (lane == 0) wsum[wid] = s;
    __syncthreads();
    if (threadIdx.x == 0) {
        double t = 0.0;
        #pragma unroll
        for (int w = 0; w < QL_THREADS / 64; ++w) t += wsum[w];
        out[0] = (float)(t * inv_count);
    }
}

extern "C" void kernel_launch(void* const* d_in, const int* in_sizes, int n_in,
                              void* d_out, int out_size, void* d_ws, size_t ws_size,
                              hipStream_t stream) {
    const float* preds  = (const float*)d_in[0];
    const float* target = (const float*)d_in[1];
    float* out = (float*)d_out;
    float* partial = (float*)d_ws;   // QL_BLOCKS floats

    int N = in_sizes[0] / 6;         // rows
    int npairs = N / 2;              // N = 8388608 is even

    ql_partial<<<QL_BLOCKS, QL_THREADS, 0, stream>>>(preds, target, partial, npairs);

    double inv_count = 1.0 / ((double)N * 5.0);
    ql_final<<<1, QL_THREADS, 0, stream>>>(partial, out, QL_BLOCKS, inv_count);
}